// Round 1
// baseline (1066.968 us; speedup 1.0000x reference)
//
#include <hip/hip_runtime.h>

#define FEAT 128

// ---------------- degree count ----------------
__global__ void degree_kernel(const int* __restrict__ src, const int* __restrict__ dst,
                              int* __restrict__ deg_out, int* __restrict__ deg_in, int E) {
    int e = blockIdx.x * blockDim.x + threadIdx.x;
    if (e < E) {
        atomicAdd(&deg_out[src[e]], 1);
        atomicAdd(&deg_in[dst[e]], 1);
    }
}

// ---------------- norms ----------------
__global__ void norm_kernel(const int* __restrict__ deg_out, const int* __restrict__ deg_in,
                            float* __restrict__ ns, float* __restrict__ nd, int n) {
    int i = blockIdx.x * blockDim.x + threadIdx.x;
    if (i < n) {
        int dou = deg_out[i]; if (dou < 1) dou = 1;
        int din = deg_in[i];  if (din < 1) din = 1;
        ns[i] = 1.0f / sqrtf((float)dou);
        nd[i] = 1.0f / sqrtf((float)din);
    }
}

// ---------------- exclusive scan (single block) ----------------
__global__ void scan_kernel(const int* __restrict__ deg, int* __restrict__ offs,
                            int* __restrict__ cursor, int n) {
    __shared__ int buf[256];
    __shared__ int carry;
    int tid = threadIdx.x;
    if (tid == 0) carry = 0;
    __syncthreads();
    for (int base = 0; base < n; base += 256) {
        int idx = base + tid;
        int v = (idx < n) ? deg[idx] : 0;
        buf[tid] = v;
        __syncthreads();
        #pragma unroll
        for (int off = 1; off < 256; off <<= 1) {
            int t = (tid >= off) ? buf[tid - off] : 0;
            __syncthreads();
            buf[tid] += t;
            __syncthreads();
        }
        int incl = buf[tid];
        int o = carry + incl - v;   // exclusive
        if (idx < n) { offs[idx] = o; cursor[idx] = o; }
        __syncthreads();
        if (tid == 0) carry += buf[255];
        __syncthreads();
    }
    if (tid == 0) offs[n] = carry;
}

// ---------------- CSR fill ----------------
__global__ void fill_kernel(const int* __restrict__ src, const int* __restrict__ dst,
                            int* __restrict__ cursor, int* __restrict__ esrc, int E) {
    int e = blockIdx.x * blockDim.x + threadIdx.x;
    if (e < E) {
        int p = atomicAdd(&cursor[dst[e]], 1);
        esrc[p] = src[e];
    }
}

// ---------------- aggregation: one wave per node ----------------
__global__ __launch_bounds__(256) void agg_kernel(const float* __restrict__ x,
                                                  const int* __restrict__ offs,
                                                  const int* __restrict__ esrc,
                                                  const float* __restrict__ ns,
                                                  const float* __restrict__ nd,
                                                  float* __restrict__ m, int n) {
    int gid = blockIdx.x * blockDim.x + threadIdx.x;
    int v = gid >> 6;
    int lane = threadIdx.x & 63;
    if (v >= n) return;
    int s0 = offs[v], s1 = offs[v + 1];
    float ax = 0.f, ay = 0.f;
    for (int j = s0; j < s1; ++j) {
        int s = esrc[j];
        float w = ns[s];
        const float2* row = (const float2*)(x + (size_t)s * FEAT);
        float2 t = row[lane];
        ax = fmaf(t.x, w, ax);
        ay = fmaf(t.y, w, ay);
    }
    float sc = nd[v];
    float2 r; r.x = ax * sc; r.y = ay * sc;
    ((float2*)(m + (size_t)v * FEAT))[lane] = r;
}

// ---------------- GEMM (N x 128) @ (128 x 128) + bias, relu ----------------
// block 256 threads, tile = 64 rows x 128 cols, 4x8 register blocking.
template<int LAST>
__global__ __launch_bounds__(256) void gemm_kernel(const float* __restrict__ M,
                                                   const float* __restrict__ W,
                                                   const float* __restrict__ bias,
                                                   float* __restrict__ out,
                                                   float* __restrict__ out2, int n) {
    __shared__ float Ms[64][36];    // pad to 36: ty/ty+2 alias is 2-way (free)
    __shared__ float Ws[32][128];
    int tid = threadIdx.x;
    int tx = tid & 15;     // col group: cols tx + 16*i
    int ty = tid >> 4;     // row group: rows ty*4 + r
    int r0 = blockIdx.x * 64;

    float acc[4][8];
    #pragma unroll
    for (int r = 0; r < 4; ++r)
        #pragma unroll
        for (int i = 0; i < 8; ++i) acc[r][i] = 0.f;

    for (int k0 = 0; k0 < FEAT; k0 += 32) {
        // stage W chunk (32 rows x 128 cols, contiguous): 1024 float4
        for (int i = tid; i < 1024; i += 256) {
            float4 v = ((const float4*)(W + (size_t)k0 * FEAT))[i];
            ((float4*)&Ws[0][0])[i] = v;
        }
        // stage M tile: 64 rows x 32 cols = 512 float4
        for (int i = tid; i < 512; i += 256) {
            int row = i >> 3, c4 = i & 7;
            float4 v = make_float4(0.f, 0.f, 0.f, 0.f);
            int gr = r0 + row;
            if (gr < n) v = *(const float4*)(M + (size_t)gr * FEAT + k0 + c4 * 4);
            *(float4*)(&Ms[row][c4 * 4]) = v;
        }
        __syncthreads();
        #pragma unroll
        for (int kk = 0; kk < 32; ++kk) {
            float wv[8];
            #pragma unroll
            for (int i = 0; i < 8; ++i) wv[i] = Ws[kk][tx + 16 * i];
            #pragma unroll
            for (int r = 0; r < 4; ++r) {
                float mv = Ms[ty * 4 + r][kk];
                #pragma unroll
                for (int i = 0; i < 8; ++i) acc[r][i] = fmaf(mv, wv[i], acc[r][i]);
            }
        }
        __syncthreads();
    }
    #pragma unroll
    for (int r = 0; r < 4; ++r) {
        int row = r0 + ty * 4 + r;
        if (row < n) {
            #pragma unroll
            for (int i = 0; i < 8; ++i) {
                int col = tx + 16 * i;
                float v = acc[r][i] + bias[col];
                v = v > 0.f ? v : 0.f;
                out[(size_t)row * FEAT + col] = v;
                if (LAST) out2[(size_t)row * FEAT + col] = (v >= 0.5f) ? 1.0f : 0.0f;
            }
        }
    }
}

extern "C" void kernel_launch(void* const* d_in, const int* in_sizes, int n_in,
                              void* d_out, int out_size, void* d_ws, size_t ws_size,
                              hipStream_t stream) {
    const float* in_feat = (const float*)d_in[0];
    const int*   src     = (const int*)d_in[1];
    const int*   dst     = (const int*)d_in[2];
    // dict order: in_feat, src, dst, W1, b1, W2, b2, W3, b3, W4, b4, W5, b5
    const float* W[5] = {(const float*)d_in[3], (const float*)d_in[5], (const float*)d_in[7],
                         (const float*)d_in[9], (const float*)d_in[11]};
    const float* B[5] = {(const float*)d_in[4], (const float*)d_in[6], (const float*)d_in[8],
                         (const float*)d_in[10], (const float*)d_in[12]};
    const int E = in_sizes[1];
    const int N = in_sizes[0] / FEAT;

    // workspace layout (bytes)
    char* ws = (char*)d_ws;
    float* m       = (float*)(ws + 0);           // N*128 f32 = 25,600,000
    float* ns      = (float*)(ws + 25600000);    // 200,000
    float* nd      = (float*)(ws + 25800000);    // 200,000
    int*   deg_out = (int*)  (ws + 26000000);    // 200,000
    int*   deg_in  = (int*)  (ws + 26200000);    // 200,000
    int*   offs    = (int*)  (ws + 26400000);    // 200,004
    int*   cursor  = (int*)  (ws + 26600016);    // 200,000
    int*   esrc    = (int*)  (ws + 26800016);    // E*4 = 3,200,000

    float* out_h = (float*)d_out;
    float* out_c = out_h + (size_t)N * FEAT;
    float* h     = out_c;   // intermediate h lives in d_out's 2nd half until last layer

    // zero the degree arrays (ws is poisoned each call)
    hipMemsetAsync(ws + 26000000, 0, 400000, stream);

    degree_kernel<<<(E + 255) / 256, 256, 0, stream>>>(src, dst, deg_out, deg_in, E);
    norm_kernel<<<(N + 255) / 256, 256, 0, stream>>>(deg_out, deg_in, ns, nd, N);
    scan_kernel<<<1, 256, 0, stream>>>(deg_in, offs, cursor, N);
    fill_kernel<<<(E + 255) / 256, 256, 0, stream>>>(src, dst, cursor, esrc, E);

    int agg_blocks = (int)(((size_t)N * 64 + 255) / 256);
    int gemm_blocks = (N + 63) / 64;

    const float* x = in_feat;
    for (int l = 0; l < 5; ++l) {
        agg_kernel<<<agg_blocks, 256, 0, stream>>>(x, offs, esrc, ns, nd, m, N);
        if (l < 4) {
            gemm_kernel<0><<<gemm_blocks, 256, 0, stream>>>(m, W[l], B[l], h, nullptr, N);
            x = h;
        } else {
            gemm_kernel<1><<<gemm_blocks, 256, 0, stream>>>(m, W[l], B[l], out_h, out_c, N);
        }
    }
}

// Round 2
// 867.580 us; speedup vs baseline: 1.2298x; 1.2298x over previous
//
#include <hip/hip_runtime.h>

#define FEAT 128

// ---------------- degree count ----------------
__global__ void degree_kernel(const int* __restrict__ src, const int* __restrict__ dst,
                              int* __restrict__ deg_out, int* __restrict__ deg_in, int E) {
    int e = blockIdx.x * blockDim.x + threadIdx.x;
    if (e < E) {
        atomicAdd(&deg_out[src[e]], 1);
        atomicAdd(&deg_in[dst[e]], 1);
    }
}

// ---------------- norms ----------------
__global__ void norm_kernel(const int* __restrict__ deg_out, const int* __restrict__ deg_in,
                            float* __restrict__ ns, float* __restrict__ nd, int n) {
    int i = blockIdx.x * blockDim.x + threadIdx.x;
    if (i < n) {
        int dou = deg_out[i]; if (dou < 1) dou = 1;
        int din = deg_in[i];  if (din < 1) din = 1;
        ns[i] = 1.0f / sqrtf((float)dou);
        nd[i] = 1.0f / sqrtf((float)din);
    }
}

// ---------------- multi-block exclusive scan (3 phases) ----------------
// phase 1: per-block (1024 elems) sums
__global__ __launch_bounds__(256) void scan_partial(const int* __restrict__ deg,
                                                    int* __restrict__ blockSums, int n) {
    __shared__ int buf[256];
    int tid = threadIdx.x;
    int base = blockIdx.x * 1024 + tid * 4;
    int s = 0;
    #pragma unroll
    for (int j = 0; j < 4; ++j) {
        int idx = base + j;
        s += (idx < n) ? deg[idx] : 0;
    }
    buf[tid] = s;
    __syncthreads();
    #pragma unroll
    for (int off = 1; off < 256; off <<= 1) {
        int t = (tid >= off) ? buf[tid - off] : 0;
        __syncthreads();
        buf[tid] += t;
        __syncthreads();
    }
    if (tid == 255) blockSums[blockIdx.x] = buf[255];
}

// phase 2: exclusive scan of block sums (nb <= 256), also writes offs[n]=total
__global__ __launch_bounds__(256) void scan_blocksums(const int* __restrict__ blockSums,
                                                      int* __restrict__ blockOffs, int nb,
                                                      int* __restrict__ offs, int n) {
    __shared__ int buf[256];
    int tid = threadIdx.x;
    int v = (tid < nb) ? blockSums[tid] : 0;
    buf[tid] = v;
    __syncthreads();
    #pragma unroll
    for (int off = 1; off < 256; off <<= 1) {
        int t = (tid >= off) ? buf[tid - off] : 0;
        __syncthreads();
        buf[tid] += t;
        __syncthreads();
    }
    if (tid < nb) blockOffs[tid] = buf[tid] - v;
    if (tid == 255) offs[n] = buf[255];
}

// phase 3: rescan + write offs/cursor
__global__ __launch_bounds__(256) void scan_write(const int* __restrict__ deg,
                                                  const int* __restrict__ blockOffs,
                                                  int* __restrict__ offs,
                                                  int* __restrict__ cursor, int n) {
    __shared__ int buf[256];
    int tid = threadIdx.x;
    int base = blockIdx.x * 1024 + tid * 4;
    int v[4];
    int s = 0;
    #pragma unroll
    for (int j = 0; j < 4; ++j) {
        int idx = base + j;
        v[j] = (idx < n) ? deg[idx] : 0;
        s += v[j];
    }
    buf[tid] = s;
    __syncthreads();
    #pragma unroll
    for (int off = 1; off < 256; off <<= 1) {
        int t = (tid >= off) ? buf[tid - off] : 0;
        __syncthreads();
        buf[tid] += t;
        __syncthreads();
    }
    int o = blockOffs[blockIdx.x] + buf[tid] - s;  // exclusive thread offset
    #pragma unroll
    for (int j = 0; j < 4; ++j) {
        int idx = base + j;
        if (idx < n) { offs[idx] = o; cursor[idx] = o; }
        o += v[j];
    }
}

// ---------------- CSR fill ----------------
__global__ void fill_kernel(const int* __restrict__ src, const int* __restrict__ dst,
                            int* __restrict__ cursor, int* __restrict__ esrc, int E) {
    int e = blockIdx.x * blockDim.x + threadIdx.x;
    if (e < E) {
        int p = atomicAdd(&cursor[dst[e]], 1);
        esrc[p] = src[e];
    }
}

// ---------------- aggregation: one wave per node ----------------
__global__ __launch_bounds__(256) void agg_kernel(const float* __restrict__ x,
                                                  const int* __restrict__ offs,
                                                  const int* __restrict__ esrc,
                                                  const float* __restrict__ ns,
                                                  const float* __restrict__ nd,
                                                  float* __restrict__ m, int n) {
    int gid = blockIdx.x * blockDim.x + threadIdx.x;
    int v = gid >> 6;
    int lane = threadIdx.x & 63;
    if (v >= n) return;
    int s0 = offs[v], s1 = offs[v + 1];
    float ax = 0.f, ay = 0.f;
    for (int j = s0; j < s1; ++j) {
        int s = esrc[j];
        float w = ns[s];
        const float2* row = (const float2*)(x + (size_t)s * FEAT);
        float2 t = row[lane];
        ax = fmaf(t.x, w, ax);
        ay = fmaf(t.y, w, ay);
    }
    float sc = nd[v];
    float2 r; r.x = ax * sc; r.y = ay * sc;
    ((float2*)(m + (size_t)v * FEAT))[lane] = r;
}

// ---------------- GEMM (N x 128) @ (128 x 128) + bias, relu ----------------
template<int LAST>
__global__ __launch_bounds__(256) void gemm_kernel(const float* __restrict__ M,
                                                   const float* __restrict__ W,
                                                   const float* __restrict__ bias,
                                                   float* __restrict__ out,
                                                   float* __restrict__ out2, int n) {
    __shared__ float Ms[64][36];
    __shared__ float Ws[32][128];
    int tid = threadIdx.x;
    int tx = tid & 15;
    int ty = tid >> 4;
    int r0 = blockIdx.x * 64;

    float acc[4][8];
    #pragma unroll
    for (int r = 0; r < 4; ++r)
        #pragma unroll
        for (int i = 0; i < 8; ++i) acc[r][i] = 0.f;

    for (int k0 = 0; k0 < FEAT; k0 += 32) {
        for (int i = tid; i < 1024; i += 256) {
            float4 v = ((const float4*)(W + (size_t)k0 * FEAT))[i];
            ((float4*)&Ws[0][0])[i] = v;
        }
        for (int i = tid; i < 512; i += 256) {
            int row = i >> 3, c4 = i & 7;
            float4 v = make_float4(0.f, 0.f, 0.f, 0.f);
            int gr = r0 + row;
            if (gr < n) v = *(const float4*)(M + (size_t)gr * FEAT + k0 + c4 * 4);
            *(float4*)(&Ms[row][c4 * 4]) = v;
        }
        __syncthreads();
        #pragma unroll
        for (int kk = 0; kk < 32; ++kk) {
            float wv[8];
            #pragma unroll
            for (int i = 0; i < 8; ++i) wv[i] = Ws[kk][tx + 16 * i];
            #pragma unroll
            for (int r = 0; r < 4; ++r) {
                float mv = Ms[ty * 4 + r][kk];
                #pragma unroll
                for (int i = 0; i < 8; ++i) acc[r][i] = fmaf(mv, wv[i], acc[r][i]);
            }
        }
        __syncthreads();
    }
    #pragma unroll
    for (int r = 0; r < 4; ++r) {
        int row = r0 + ty * 4 + r;
        if (row < n) {
            #pragma unroll
            for (int i = 0; i < 8; ++i) {
                int col = tx + 16 * i;
                float v = acc[r][i] + bias[col];
                v = v > 0.f ? v : 0.f;
                out[(size_t)row * FEAT + col] = v;
                if (LAST) out2[(size_t)row * FEAT + col] = (v >= 0.5f) ? 1.0f : 0.0f;
            }
        }
    }
}

extern "C" void kernel_launch(void* const* d_in, const int* in_sizes, int n_in,
                              void* d_out, int out_size, void* d_ws, size_t ws_size,
                              hipStream_t stream) {
    const float* in_feat = (const float*)d_in[0];
    const int*   src     = (const int*)d_in[1];
    const int*   dst     = (const int*)d_in[2];
    const float* W[5] = {(const float*)d_in[3], (const float*)d_in[5], (const float*)d_in[7],
                         (const float*)d_in[9], (const float*)d_in[11]};
    const float* B[5] = {(const float*)d_in[4], (const float*)d_in[6], (const float*)d_in[8],
                         (const float*)d_in[10], (const float*)d_in[12]};
    const int E = in_sizes[1];
    const int N = in_sizes[0] / FEAT;

    // workspace layout (bytes)
    char* ws = (char*)d_ws;
    float* m         = (float*)(ws + 0);           // N*128 f32 = 25,600,000
    float* ns        = (float*)(ws + 25600000);    // 200,000
    float* nd        = (float*)(ws + 25800000);    // 200,000
    int*   deg_out   = (int*)  (ws + 26000000);    // 200,000
    int*   deg_in    = (int*)  (ws + 26200000);    // 200,000
    int*   offs      = (int*)  (ws + 26400000);    // 200,004
    int*   cursor    = (int*)  (ws + 26600016);    // 200,000
    int*   esrc      = (int*)  (ws + 26800016);    // E*4 = 3,200,000
    int*   blockSums = (int*)  (ws + 30000016);    // 1,024
    int*   blockOffs = (int*)  (ws + 30001040);    // 1,024

    float* out_h = (float*)d_out;
    float* out_c = out_h + (size_t)N * FEAT;
    float* h     = out_c;

    hipMemsetAsync(ws + 26000000, 0, 400000, stream);

    const int nb = (N + 1023) / 1024;  // 49 for N=50000

    degree_kernel<<<(E + 255) / 256, 256, 0, stream>>>(src, dst, deg_out, deg_in, E);
    norm_kernel<<<(N + 255) / 256, 256, 0, stream>>>(deg_out, deg_in, ns, nd, N);
    scan_partial<<<nb, 256, 0, stream>>>(deg_in, blockSums, N);
    scan_blocksums<<<1, 256, 0, stream>>>(blockSums, blockOffs, nb, offs, N);
    scan_write<<<nb, 256, 0, stream>>>(deg_in, blockOffs, offs, cursor, N);
    fill_kernel<<<(E + 255) / 256, 256, 0, stream>>>(src, dst, cursor, esrc, E);

    int agg_blocks = (int)(((size_t)N * 64 + 255) / 256);
    int gemm_blocks = (N + 63) / 64;

    const float* x = in_feat;
    for (int l = 0; l < 5; ++l) {
        agg_kernel<<<agg_blocks, 256, 0, stream>>>(x, offs, esrc, ns, nd, m, N);
        if (l < 4) {
            gemm_kernel<0><<<gemm_blocks, 256, 0, stream>>>(m, W[l], B[l], h, nullptr, N);
            x = h;
        } else {
            gemm_kernel<1><<<gemm_blocks, 256, 0, stream>>>(m, W[l], B[l], out_h, out_c, N);
        }
    }
}

// Round 3
// 654.107 us; speedup vs baseline: 1.6312x; 1.3264x over previous
//
#include <hip/hip_runtime.h>

#define FEAT 128

// ---------------- degree count ----------------
__global__ void degree_kernel(const int* __restrict__ src, const int* __restrict__ dst,
                              int* __restrict__ deg_out, int* __restrict__ deg_in, int E) {
    int e = blockIdx.x * blockDim.x + threadIdx.x;
    if (e < E) {
        atomicAdd(&deg_out[src[e]], 1);
        atomicAdd(&deg_in[dst[e]], 1);
    }
}

// ---------------- norms ----------------
__global__ void norm_kernel(const int* __restrict__ deg_out, const int* __restrict__ deg_in,
                            float* __restrict__ ns, float* __restrict__ nd, int n) {
    int i = blockIdx.x * blockDim.x + threadIdx.x;
    if (i < n) {
        int dou = deg_out[i]; if (dou < 1) dou = 1;
        int din = deg_in[i];  if (din < 1) din = 1;
        ns[i] = 1.0f / sqrtf((float)dou);
        nd[i] = 1.0f / sqrtf((float)din);
    }
}

// ---------------- multi-block exclusive scan (3 phases) ----------------
__global__ __launch_bounds__(256) void scan_partial(const int* __restrict__ deg,
                                                    int* __restrict__ blockSums, int n) {
    __shared__ int buf[256];
    int tid = threadIdx.x;
    int base = blockIdx.x * 1024 + tid * 4;
    int s = 0;
    #pragma unroll
    for (int j = 0; j < 4; ++j) {
        int idx = base + j;
        s += (idx < n) ? deg[idx] : 0;
    }
    buf[tid] = s;
    __syncthreads();
    #pragma unroll
    for (int off = 1; off < 256; off <<= 1) {
        int t = (tid >= off) ? buf[tid - off] : 0;
        __syncthreads();
        buf[tid] += t;
        __syncthreads();
    }
    if (tid == 255) blockSums[blockIdx.x] = buf[255];
}

__global__ __launch_bounds__(256) void scan_blocksums(const int* __restrict__ blockSums,
                                                      int* __restrict__ blockOffs, int nb,
                                                      int* __restrict__ offs, int n) {
    __shared__ int buf[256];
    int tid = threadIdx.x;
    int v = (tid < nb) ? blockSums[tid] : 0;
    buf[tid] = v;
    __syncthreads();
    #pragma unroll
    for (int off = 1; off < 256; off <<= 1) {
        int t = (tid >= off) ? buf[tid - off] : 0;
        __syncthreads();
        buf[tid] += t;
        __syncthreads();
    }
    if (tid < nb) blockOffs[tid] = buf[tid] - v;
    if (tid == 255) offs[n] = buf[255];
}

__global__ __launch_bounds__(256) void scan_write(const int* __restrict__ deg,
                                                  const int* __restrict__ blockOffs,
                                                  int* __restrict__ offs,
                                                  int* __restrict__ cursor, int n) {
    __shared__ int buf[256];
    int tid = threadIdx.x;
    int base = blockIdx.x * 1024 + tid * 4;
    int v[4];
    int s = 0;
    #pragma unroll
    for (int j = 0; j < 4; ++j) {
        int idx = base + j;
        v[j] = (idx < n) ? deg[idx] : 0;
        s += v[j];
    }
    buf[tid] = s;
    __syncthreads();
    #pragma unroll
    for (int off = 1; off < 256; off <<= 1) {
        int t = (tid >= off) ? buf[tid - off] : 0;
        __syncthreads();
        buf[tid] += t;
        __syncthreads();
    }
    int o = blockOffs[blockIdx.x] + buf[tid] - s;
    #pragma unroll
    for (int j = 0; j < 4; ++j) {
        int idx = base + j;
        if (idx < n) { offs[idx] = o; cursor[idx] = o; }
        o += v[j];
    }
}

// ---------------- CSR fill (+ pre-scaled edge weights) ----------------
__global__ void fill_kernel(const int* __restrict__ src, const int* __restrict__ dst,
                            const float* __restrict__ ns,
                            int* __restrict__ cursor, int* __restrict__ esrc,
                            float* __restrict__ ew, int E) {
    int e = blockIdx.x * blockDim.x + threadIdx.x;
    if (e < E) {
        int s = src[e];
        int p = atomicAdd(&cursor[dst[e]], 1);
        esrc[p] = s;
        ew[p] = ns[s];
    }
}

// ---------------- aggregation: one wave per node, unroll x4 ----------------
__global__ __launch_bounds__(256) void agg_kernel(const float* __restrict__ x,
                                                  const int* __restrict__ offs,
                                                  const int* __restrict__ esrc,
                                                  const float* __restrict__ ew,
                                                  const float* __restrict__ nd,
                                                  float* __restrict__ m, int n) {
    int gid = blockIdx.x * blockDim.x + threadIdx.x;
    int v = gid >> 6;
    int lane = threadIdx.x & 63;
    if (v >= n) return;
    int s0 = offs[v], s1 = offs[v + 1];
    float ax0 = 0.f, ay0 = 0.f, ax1 = 0.f, ay1 = 0.f;
    float ax2 = 0.f, ay2 = 0.f, ax3 = 0.f, ay3 = 0.f;
    int j = s0;
    for (; j + 4 <= s1; j += 4) {
        int sa = esrc[j], sb = esrc[j + 1], sc = esrc[j + 2], sd = esrc[j + 3];
        float wa = ew[j], wb = ew[j + 1], wc = ew[j + 2], wd = ew[j + 3];
        float2 ta = ((const float2*)(x + (size_t)sa * FEAT))[lane];
        float2 tb = ((const float2*)(x + (size_t)sb * FEAT))[lane];
        float2 tc = ((const float2*)(x + (size_t)sc * FEAT))[lane];
        float2 td = ((const float2*)(x + (size_t)sd * FEAT))[lane];
        ax0 = fmaf(ta.x, wa, ax0); ay0 = fmaf(ta.y, wa, ay0);
        ax1 = fmaf(tb.x, wb, ax1); ay1 = fmaf(tb.y, wb, ay1);
        ax2 = fmaf(tc.x, wc, ax2); ay2 = fmaf(tc.y, wc, ay2);
        ax3 = fmaf(td.x, wd, ax3); ay3 = fmaf(td.y, wd, ay3);
    }
    for (; j < s1; ++j) {
        int s = esrc[j];
        float w = ew[j];
        float2 t = ((const float2*)(x + (size_t)s * FEAT))[lane];
        ax0 = fmaf(t.x, w, ax0); ay0 = fmaf(t.y, w, ay0);
    }
    float sc_ = nd[v];
    float2 r;
    r.x = ((ax0 + ax1) + (ax2 + ax3)) * sc_;
    r.y = ((ay0 + ay1) + (ay2 + ay3)) * sc_;
    ((float2*)(m + (size_t)v * FEAT))[lane] = r;
}

// ---------------- GEMM (N x 128) @ (128 x 128) + bias, relu ----------------
// 64-row x 128-col tile, transposed M in LDS, all-b128 LDS reads.
template<int LAST>
__global__ __launch_bounds__(256) void gemm_kernel(const float* __restrict__ M,
                                                   const float* __restrict__ W,
                                                   const float* __restrict__ bias,
                                                   float* __restrict__ out,
                                                   float* __restrict__ out2, int n) {
    __shared__ float MsT[32][68];   // [k][row], stride 68 keeps 16B align + breaks conflicts
    __shared__ float Ws[32][128];
    int tid = threadIdx.x;
    int tx = tid & 15;     // cols 4*tx..+3 and 64+4*tx..+3
    int ty = tid >> 4;     // rows ty*4..+3
    int r0 = blockIdx.x * 64;

    float acc[4][8];
    #pragma unroll
    for (int r = 0; r < 4; ++r)
        #pragma unroll
        for (int i = 0; i < 8; ++i) acc[r][i] = 0.f;

    for (int k0 = 0; k0 < FEAT; k0 += 32) {
        // stage W chunk (32 rows x 128 cols contiguous): 1024 float4
        for (int i = tid; i < 1024; i += 256) {
            ((float4*)&Ws[0][0])[i] = ((const float4*)(W + (size_t)k0 * FEAT))[i];
        }
        // stage M tile transposed: 64 rows x 32 k
        for (int i = tid; i < 512; i += 256) {
            int row = i >> 3, c4 = i & 7;
            int gr = r0 + row;
            float4 v = make_float4(0.f, 0.f, 0.f, 0.f);
            if (gr < n) v = *(const float4*)(M + (size_t)gr * FEAT + k0 + c4 * 4);
            MsT[c4 * 4 + 0][row] = v.x;
            MsT[c4 * 4 + 1][row] = v.y;
            MsT[c4 * 4 + 2][row] = v.z;
            MsT[c4 * 4 + 3][row] = v.w;
        }
        __syncthreads();
        #pragma unroll
        for (int kk = 0; kk < 32; ++kk) {
            float4 a4 = *(const float4*)&MsT[kk][ty * 4];
            float4 w0 = *(const float4*)&Ws[kk][tx * 4];
            float4 w1 = *(const float4*)&Ws[kk][64 + tx * 4];
            float a[4] = {a4.x, a4.y, a4.z, a4.w};
            float w[8] = {w0.x, w0.y, w0.z, w0.w, w1.x, w1.y, w1.z, w1.w};
            #pragma unroll
            for (int r = 0; r < 4; ++r)
                #pragma unroll
                for (int i = 0; i < 8; ++i)
                    acc[r][i] = fmaf(a[r], w[i], acc[r][i]);
        }
        __syncthreads();
    }

    float4 b0 = *(const float4*)&bias[tx * 4];
    float4 b1 = *(const float4*)&bias[64 + tx * 4];
    #pragma unroll
    for (int r = 0; r < 4; ++r) {
        int row = r0 + ty * 4 + r;
        if (row < n) {
            float4 v0, v1;
            v0.x = acc[r][0] + b0.x; v0.y = acc[r][1] + b0.y;
            v0.z = acc[r][2] + b0.z; v0.w = acc[r][3] + b0.w;
            v1.x = acc[r][4] + b1.x; v1.y = acc[r][5] + b1.y;
            v1.z = acc[r][6] + b1.z; v1.w = acc[r][7] + b1.w;
            v0.x = v0.x > 0.f ? v0.x : 0.f; v0.y = v0.y > 0.f ? v0.y : 0.f;
            v0.z = v0.z > 0.f ? v0.z : 0.f; v0.w = v0.w > 0.f ? v0.w : 0.f;
            v1.x = v1.x > 0.f ? v1.x : 0.f; v1.y = v1.y > 0.f ? v1.y : 0.f;
            v1.z = v1.z > 0.f ? v1.z : 0.f; v1.w = v1.w > 0.f ? v1.w : 0.f;
            *(float4*)(out + (size_t)row * FEAT + tx * 4) = v0;
            *(float4*)(out + (size_t)row * FEAT + 64 + tx * 4) = v1;
            if (LAST) {
                float4 c0, c1;
                c0.x = v0.x >= 0.5f ? 1.f : 0.f; c0.y = v0.y >= 0.5f ? 1.f : 0.f;
                c0.z = v0.z >= 0.5f ? 1.f : 0.f; c0.w = v0.w >= 0.5f ? 1.f : 0.f;
                c1.x = v1.x >= 0.5f ? 1.f : 0.f; c1.y = v1.y >= 0.5f ? 1.f : 0.f;
                c1.z = v1.z >= 0.5f ? 1.f : 0.f; c1.w = v1.w >= 0.5f ? 1.f : 0.f;
                *(float4*)(out2 + (size_t)row * FEAT + tx * 4) = c0;
                *(float4*)(out2 + (size_t)row * FEAT + 64 + tx * 4) = c1;
            }
        }
    }
}

extern "C" void kernel_launch(void* const* d_in, const int* in_sizes, int n_in,
                              void* d_out, int out_size, void* d_ws, size_t ws_size,
                              hipStream_t stream) {
    const float* in_feat = (const float*)d_in[0];
    const int*   src     = (const int*)d_in[1];
    const int*   dst     = (const int*)d_in[2];
    const float* W[5] = {(const float*)d_in[3], (const float*)d_in[5], (const float*)d_in[7],
                         (const float*)d_in[9], (const float*)d_in[11]};
    const float* B[5] = {(const float*)d_in[4], (const float*)d_in[6], (const float*)d_in[8],
                         (const float*)d_in[10], (const float*)d_in[12]};
    const int E = in_sizes[1];
    const int N = in_sizes[0] / FEAT;

    // workspace layout (bytes) — m now lives in d_out (in-place gemm is safe:
    // each 64-row block is read only by the block that writes it)
    char* ws = (char*)d_ws;
    float* ns        = (float*)(ws + 0);          // 200,000
    float* nd        = (float*)(ws + 200000);     // 200,000
    int*   deg_out   = (int*)  (ws + 400000);     // 200,000
    int*   deg_in    = (int*)  (ws + 600000);     // 200,000
    int*   offs      = (int*)  (ws + 800000);     // 200,016
    int*   cursor    = (int*)  (ws + 1000016);    // 200,000
    int*   esrc      = (int*)  (ws + 1200016);    // E*4 = 3,200,000
    float* ew        = (float*)(ws + 4400016);    // E*4 = 3,200,000
    int*   blockSums = (int*)  (ws + 7600016);    // 1,024
    int*   blockOffs = (int*)  (ws + 7601040);    // 1,024

    float* out_h = (float*)d_out;
    float* out_c = out_h + (size_t)N * FEAT;
    float* m     = out_h;   // aggregation scratch aliases final-h region
    float* h     = out_c;   // intermediate h aliases threshold region

    hipMemsetAsync(ws + 400000, 0, 400000, stream);   // zero deg_out/deg_in

    const int nb = (N + 1023) / 1024;

    degree_kernel<<<(E + 255) / 256, 256, 0, stream>>>(src, dst, deg_out, deg_in, E);
    norm_kernel<<<(N + 255) / 256, 256, 0, stream>>>(deg_out, deg_in, ns, nd, N);
    scan_partial<<<nb, 256, 0, stream>>>(deg_in, blockSums, N);
    scan_blocksums<<<1, 256, 0, stream>>>(blockSums, blockOffs, nb, offs, N);
    scan_write<<<nb, 256, 0, stream>>>(deg_in, blockOffs, offs, cursor, N);
    fill_kernel<<<(E + 255) / 256, 256, 0, stream>>>(src, dst, ns, cursor, esrc, ew, E);

    int agg_blocks = (int)(((size_t)N * 64 + 255) / 256);
    int gemm_blocks = (N + 63) / 64;

    const float* x = in_feat;
    for (int l = 0; l < 5; ++l) {
        agg_kernel<<<agg_blocks, 256, 0, stream>>>(x, offs, esrc, ew, nd, m, N);
        if (l < 4) {
            gemm_kernel<0><<<gemm_blocks, 256, 0, stream>>>(m, W[l], B[l], h, nullptr, N);
            x = h;
        } else {
            gemm_kernel<1><<<gemm_blocks, 256, 0, stream>>>(m, W[l], B[l], out_h, out_c, N);
        }
    }
}